// Round 6
// baseline (175.430 us; speedup 1.0000x reference)
//
#include <hip/hip_runtime.h>

// STFT round-trip collapse:
//   conc == ft                      (mag/phase identity: mag*cos(atan2(i,r)) = r, etc.)
//   fwd composed with inv == diag(win)/SCALE   (pinv(fb)@fb = I; fb is 1026x1024 full column rank)
//   => out[b,u] = wav[b,u] * W1[u+PAD] / (EPS + W2[u+PAD])
// where W1/W2 sum win / win^2 over the <=4 frames overlapping padded sample t=u+PAD.
// Reflect padding only influences samples cropped by y[:, PAD:-PAD]. Pure streaming kernel.
//
// R4: validated (absmax 0.031), dur_us=129.5 with top-5 all harness poison fills.
// R5: __builtin_nontemporal_* requires a NATIVE vector type, not HIP_vector_type
//     (float4 is a class) — use ext_vector_type(4) instead.

constexpr int kCols     = 2097152;       // T
constexpr int kRow4     = kCols / 4;     // float4 per row (power of 2)
constexpr int kHop      = 256;
constexpr int kPad      = 512;           // FILTER_LENGTH/2
constexpr int kMaxFrame = 8192;          // nF - 1

typedef float fvec4 __attribute__((ext_vector_type(4)));

__global__ __launch_bounds__(256) void stft_roundtrip_kernel(
    const fvec4* __restrict__ wav,
    const float* __restrict__ sqw,       // square_window = win^2, 1024 floats
    fvec4* __restrict__ out,
    int total4)                          // B * kRow4
{
    const int gid = blockIdx.x * blockDim.x + threadIdx.x;
    if (gid >= total4) return;

    const int col4 = gid & (kRow4 - 1);  // float4 column group within a row
    const int u0   = col4 * 4;

    // Per-column gain = W1 / (EPS + W2), from the actual square_window input.
    fvec4 g;
#pragma unroll
    for (int q = 0; q < 4; ++q) {
        const int t   = u0 + q + kPad;
        const int fhi = t >> 8;          // highest candidate frame index
        const int m   = t & 255;         // window offset phase
        float w1 = 0.0f, w2 = 0.0f;
#pragma unroll
        for (int j = 0; j < 4; ++j) {
            const int f = fhi - j;       // frame index; window pos k = m + 256*j in [0,1024)
            if (f >= 0 && f <= kMaxFrame) {
                const float s = sqw[m + kHop * j];
                w2 += s;
                w1 += sqrtf(s);          // win[k] >= 0 (Hann)
            }
        }
        g[q] = w1 / (1e-9f + w2);
    }

    fvec4 v = __builtin_nontemporal_load(&wav[gid]);
    v *= g;
    __builtin_nontemporal_store(v, &out[gid]);
}

extern "C" void kernel_launch(void* const* d_in, const int* in_sizes, int n_in,
                              void* d_out, int out_size, void* d_ws, size_t ws_size,
                              hipStream_t stream)
{
    const fvec4* wav = (const fvec4*)d_in[0];   // (B, 2097152) f32
    const float* sqw = (const float*)d_in[3];   // (1024,) f32
    fvec4* out = (fvec4*)d_out;                 // (B, 2097152) f32

    const int total4  = in_sizes[0] / 4;        // B * kRow4 = 4,194,304
    const int threads = 256;
    const int blocks  = (total4 + threads - 1) / threads;  // 16384
    stft_roundtrip_kernel<<<blocks, threads, 0, stream>>>(wav, sqw, out, total4);
}

// Round 7
// 134.102 us; speedup vs baseline: 1.3082x; 1.3082x over previous
//
#include <hip/hip_runtime.h>

// STFT round-trip collapse:
//   conc == ft                      (mag/phase identity: mag*cos(atan2(i,r)) = r, etc.)
//   fwd composed with inv == diag(win)/SCALE   (pinv(fb)@fb = I; fb is 1026x1024 full column rank)
//   => out[b,u] = wav[b,u] * W1[u+PAD] / (EPS + W2[u+PAD])
// where W1/W2 sum win / win^2 over the <=4 frames overlapping padded sample t=u+PAD.
// Reflect padding only influences samples cropped by y[:, PAD:-PAD]. Pure streaming kernel.
//
// R4: batch-loop version, kernel ~36us (runtime trip count -> 1 outstanding load).
// R6: loop-free + nontemporal REGRESSED (kernel 82us, VALUBusy 47% from 8x gain
//     recompute; nt hurt cache path). Revert.
// R7: batch loop with compile-time kBatch, load-all-8 then store-all-8 to get
//     8 outstanding loads/wave (64/SIMD) -> HBM streaming bound. No nt hints.

constexpr int kCols     = 2097152;       // T
constexpr int kRow4     = kCols / 4;     // float4 per row
constexpr int kBatch    = 8;
constexpr int kHop      = 256;
constexpr int kPad      = 512;           // FILTER_LENGTH/2
constexpr int kMaxFrame = 8192;          // nF - 1

typedef float fvec4 __attribute__((ext_vector_type(4)));

__global__ __launch_bounds__(256) void stft_roundtrip_kernel(
    const fvec4* __restrict__ wav,
    const float* __restrict__ sqw,       // square_window = win^2, 1024 floats
    fvec4* __restrict__ out)
{
    const int tid = blockIdx.x * blockDim.x + threadIdx.x;
    if (tid >= kRow4) return;
    const int u0 = tid * 4;

    // Per-column gain = W1 / (EPS + W2), from the actual square_window input.
    // Computed once per column, amortized over all 8 batch rows.
    fvec4 g;
#pragma unroll
    for (int q = 0; q < 4; ++q) {
        const int t   = u0 + q + kPad;
        const int fhi = t >> 8;          // highest candidate frame index
        const int m   = t & 255;         // window offset phase
        float w1 = 0.0f, w2 = 0.0f;
#pragma unroll
        for (int j = 0; j < 4; ++j) {
            const int f = fhi - j;       // frame index; window pos k = m + 256*j in [0,1024)
            if (f >= 0 && f <= kMaxFrame) {
                const float s = sqw[m + kHop * j];
                w2 += s;
                w1 += sqrtf(s);          // win[k] >= 0 (Hann)
            }
        }
        g[q] = w1 / (1e-9f + w2);
    }

    // Issue all 8 row loads back-to-back (8 outstanding vmem ops per wave),
    // then multiply and store. Fully coalesced dwordx4 both ways.
    fvec4 v[kBatch];
#pragma unroll
    for (int b = 0; b < kBatch; ++b)
        v[b] = wav[(size_t)b * kRow4 + (size_t)tid];
#pragma unroll
    for (int b = 0; b < kBatch; ++b)
        out[(size_t)b * kRow4 + (size_t)tid] = v[b] * g;
}

extern "C" void kernel_launch(void* const* d_in, const int* in_sizes, int n_in,
                              void* d_out, int out_size, void* d_ws, size_t ws_size,
                              hipStream_t stream)
{
    const fvec4* wav = (const fvec4*)d_in[0];   // (8, 2097152) f32
    const float* sqw = (const float*)d_in[3];   // (1024,) f32
    fvec4* out = (fvec4*)d_out;                 // (8, 2097152) f32

    const int threads = 256;
    const int blocks  = (kRow4 + threads - 1) / threads;   // 2048
    stft_roundtrip_kernel<<<blocks, threads, 0, stream>>>(wav, sqw, out);
}